// Round 8
// baseline (426.232 us; speedup 1.0000x reference)
//
#include <hip/hip_runtime.h>
#include <hip/hip_bf16.h>
#include <stdint.h>

// Problem constants
constexpr int NB = 2;        // batch
constexpr int NT = 4096;     // seq len
constexpr int NH = 16;       // heads
constexpr int ND = 128;      // head dim
constexpr int HID = NH * ND;         // 2048
constexpr int QKV_N = 3 * HID;       // 6144
constexpr int ROWS = NB * NT;        // 8192
constexpr int CHUNK = 64;            // scan chunk length
constexpr int NCH = NT / CHUNK;      // 64 chunks

typedef __bf16 bf16x8 __attribute__((ext_vector_type(8)));
typedef float  f32x4  __attribute__((ext_vector_type(4)));

__device__ inline unsigned short f2bf(float f) {       // RNE fp32->bf16
    unsigned u = __builtin_bit_cast(unsigned, f);
    u += 0x7fffu + ((u >> 16) & 1u);
    return (unsigned short)(u >> 16);
}
__device__ inline float bf2f(unsigned short b) {
    unsigned u = ((unsigned)b) << 16;
    return __builtin_bit_cast(float, u);
}

// ---------------- cast fp32 -> bf16 (flat, float4-vectorized) -------------
__global__ void cast_kernel(const float* __restrict__ in,
                            unsigned short* __restrict__ out, size_t n4) {
    size_t i = blockIdx.x * (size_t)blockDim.x + threadIdx.x;
    size_t stride = (size_t)gridDim.x * blockDim.x;
    for (; i < n4; i += stride) {
        float4 v = reinterpret_cast<const float4*>(in)[i];
        ushort4 o;
        o.x = f2bf(v.x); o.y = f2bf(v.y); o.z = f2bf(v.z); o.w = f2bf(v.w);
        reinterpret_cast<ushort4*>(out)[i] = o;
    }
}

// ------------- transpose + cast: in f32 [R][Cn] -> out bf16 [Cn][R] -------
__global__ __launch_bounds__(256) void transpose_cast(
        const float* __restrict__ in, unsigned short* __restrict__ out,
        int R, int Cn) {
    __shared__ float tile[32][33];
    const int c  = threadIdx.x & 31;
    const int r8 = threadIdx.x >> 5;          // 0..7
    const int r0 = blockIdx.y * 32, c0 = blockIdx.x * 32;
    #pragma unroll
    for (int i = 0; i < 32; i += 8)
        tile[r8 + i][c] = in[(size_t)(r0 + r8 + i) * Cn + c0 + c];
    __syncthreads();
    #pragma unroll
    for (int i = 0; i < 32; i += 8)
        out[(size_t)(c0 + r8 + i) * R + r0 + c] = f2bf(tile[c][r8 + i]);
}

// =================== 256x256 8-wave 4-phase/2-K-tile GEMM ==================
// Round 8: identical schedule/ledger to round 7, but the double buffers are
// SIX DISTINCT __shared__ objects (As0, As1, B0h0, B0h1, B1h0, B1h1) so each
// phase's ds_reads provably do not alias the in-flight global_load_lds DMA
// (LLVM alias analysis is per-object). This removes the compiler-inserted
// vmcnt(0) drains before each read group — the hand WAITV ledger becomes the
// only vmcnt control. B tiles are re-rowed: object h{s} row r = wn*32 + r32
// holds C-col wn*64 + s*32 + r32.
// Ledger (issue order identical to r7):
//   P1: WAITV(6) drains tile-T0 (As0 4 + B0h0 2 + B0h1 2)
//   P3: WAITV(8) drains As1 4 + B1h0 2
//   P4: WAITV(8) drains B1h1 2

#define WAITV(N) asm volatile("s_waitcnt vmcnt(" #N ")" ::: "memory")
#define BARB()   __builtin_amdgcn_s_barrier()

__device__ __forceinline__ void gll(const unsigned short* src, unsigned short* dst) {
    __builtin_amdgcn_global_load_lds(
        (const __attribute__((address_space(1))) void*)src,
        (__attribute__((address_space(3))) void*)dst, 16, 0, 0);
}

// A sub 0 = rows {[0,64) u [128,192)} (mh0 rows of both wm); sub 1 = +64.
__device__ __forceinline__ void stage_a(const unsigned short* Ag, int K, int k0,
                                        unsigned short* lds, int sub,
                                        int wid, int lane) {
    const int rl = wid * 8 + (lane >> 3);
    const int ce = ((lane & 7) ^ (lane >> 3)) * 8;   // inverse-swizzled col
    #pragma unroll
    for (int j = 0; j < 2; ++j) {
        int row = j * 128 + sub * 64;
        gll(Ag + (size_t)(row + rl) * K + k0 + ce,
            lds + (row + wid * 8) * 64);
    }
}
// B half-object stage: object holds 128 rows; row = group*32 + (wid&3)*8 + l>>3,
// global row = group*64 + sub*32 + (wid&3)*8 + l>>3, group = (wid>>2) + 2*j.
__device__ __forceinline__ void stage_bh(const unsigned short* Bg, int K, int k0,
                                         unsigned short* ldsh, int sub,
                                         int wid, int lane) {
    const int ce = ((lane & 7) ^ (lane >> 3)) * 8;
    const int rchunk = (wid & 3) * 8;
    #pragma unroll
    for (int j = 0; j < 2; ++j) {
        int group = (wid >> 2) + 2 * j;
        gll(Bg + (size_t)(group * 64 + sub * 32 + rchunk + (lane >> 3)) * K + k0 + ce,
            ldsh + (group * 32 + rchunk) * 64);
    }
}

__device__ __forceinline__ bf16x8 ld_frag(const unsigned short* tile,
                                          int r, int kk, int fq) {
    int slot = (kk * 4 + fq) ^ (r & 7);          // swizzled 16B slot
    return *reinterpret_cast<const bf16x8*>(tile + r * 64 + slot * 8);
}

template <int MH>
__device__ __forceinline__ void read_a(const unsigned short* T, int wm,
                                       int fr, int fq, bf16x8 af[4][2]) {
    #pragma unroll
    for (int m = 0; m < 4; ++m) {
        int r = wm * 128 + MH * 64 + m * 16 + fr;
        af[m][0] = ld_frag(T, r, 0, fq);
        af[m][1] = ld_frag(T, r, 1, fq);
    }
}
// read one B half-object: r = wn*32 + n*16 + fr  (r&7 == fr&7, swizzle ok)
template <int NHH>
__device__ __forceinline__ void read_bh(const unsigned short* H, int wn,
                                        int fr, int fq, bf16x8 bfr[4][2]) {
    #pragma unroll
    for (int n = 0; n < 2; ++n) {
        int r = wn * 32 + n * 16 + fr;
        bfr[NHH * 2 + n][0] = ld_frag(H, r, 0, fq);
        bfr[NHH * 2 + n][1] = ld_frag(H, r, 1, fq);
    }
}

// 32 MFMA: both M-halves against one N-half (NHH) of the current tile.
template <int NHH>
__device__ __forceinline__ void mfma_col(f32x4 acc[8][4],
                                         const bf16x8 aflo[4][2],
                                         const bf16x8 afhi[4][2],
                                         const bf16x8 bfr[4][2]) {
    __builtin_amdgcn_s_setprio(1);
    #pragma unroll
    for (int kk = 0; kk < 2; ++kk) {
        #pragma unroll
        for (int m = 0; m < 4; ++m)
            #pragma unroll
            for (int n = 0; n < 2; ++n)
                acc[m][NHH * 2 + n] =
                    __builtin_amdgcn_mfma_f32_16x16x32_bf16(
                        aflo[m][kk], bfr[NHH * 2 + n][kk],
                        acc[m][NHH * 2 + n], 0, 0, 0);
        #pragma unroll
        for (int m = 0; m < 4; ++m)
            #pragma unroll
            for (int n = 0; n < 2; ++n)
                acc[4 + m][NHH * 2 + n] =
                    __builtin_amdgcn_mfma_f32_16x16x32_bf16(
                        afhi[m][kk], bfr[NHH * 2 + n][kk],
                        acc[4 + m][NHH * 2 + n], 0, 0, 0);
    }
    __builtin_amdgcn_s_setprio(0);
}

template <typename OUT_T>
__global__ __launch_bounds__(512, 2) void gemm256(
        const unsigned short* __restrict__ A,   // [M][K] bf16
        const unsigned short* __restrict__ Bt,  // [N][K] bf16
        OUT_T* __restrict__ C,                  // [M][N]
        int M, int N, int K, int nbx, int cpx) {
    __shared__ unsigned short As0[256 * 64];
    __shared__ unsigned short As1[256 * 64];
    __shared__ unsigned short B0h0[128 * 64];
    __shared__ unsigned short B0h1[128 * 64];
    __shared__ unsigned short B1h0[128 * 64];
    __shared__ unsigned short B1h1[128 * 64];

    const int bid = blockIdx.x;
    const int wk  = (bid & 7) * cpx + (bid >> 3);   // T1 XCD swizzle
    const int bx  = wk % nbx, by = wk / nbx;
    const int tid = threadIdx.x, wid = tid >> 6, lane = tid & 63;
    const int wm  = wid >> 2, wn = wid & 3;
    const int fr  = lane & 15, fq = lane >> 4;

    const unsigned short* Ag = A  + (size_t)by * 256 * K;
    const unsigned short* Bg = Bt + (size_t)bx * 256 * K;

    f32x4 acc[8][4] = {};
    bf16x8 aflo[4][2], afhi[4][2], bfr[4][2];

    // prologue: 14 loads — tile0 complete + tile1 A/Bh0 (B1h1 staged in P1(0))
    stage_a (Ag, K, 0, As0, 0, wid, lane);
    stage_a (Ag, K, 0, As0, 1, wid, lane);
    stage_bh(Bg, K, 0, B0h0, 0, wid, lane);
    stage_bh(Bg, K, 0, B0h1, 1, wid, lane);
    stage_a (Ag, K, 64, As1, 0, wid, lane);
    stage_a (Ag, K, 64, As1, 1, wid, lane);
    stage_bh(Bg, K, 64, B1h0, 0, wid, lane);

    const int NK = K / 64;              // even (K=2048 -> 32)
    const int NITER = NK / 2;
    for (int k = 0; k < NITER - 1; ++k) {
        const int kT1 = (2 * k + 1) * 64;   // this iter's T1 (B1h1)
        const int kA  = (2 * k + 2) * 64;   // next T0 -> buf0 objects
        const int kB  = (2 * k + 3) * 64;   // next T1 -> buf1 objects
        // ---- P1: tile T0, N-half 0 (also stage B1h1 of THIS T1)
        WAITV(6);
        stage_bh(Bg, K, kT1, B1h1, 1, wid, lane);
        read_a<0>(As0, wm, fr, fq, aflo);
        read_a<1>(As0, wm, fr, fq, afhi);
        read_bh<0>(B0h0, wn, fr, fq, bfr);
        BARB();
        mfma_col<0>(acc, aflo, afhi, bfr);
        BARB();
        // ---- P2: tile T0, N-half 1 (stage next-T0 A + B0h0)
        stage_a (Ag, K, kA, As0, 0, wid, lane);
        stage_a (Ag, K, kA, As0, 1, wid, lane);
        stage_bh(Bg, K, kA, B0h0, 0, wid, lane);
        read_bh<1>(B0h1, wn, fr, fq, bfr);
        BARB();
        mfma_col<1>(acc, aflo, afhi, bfr);
        BARB();
        // ---- P3: tile T1, N-half 0 (stage next-T0 B0h1)
        WAITV(8);
        stage_bh(Bg, K, kA, B0h1, 1, wid, lane);
        read_a<0>(As1, wm, fr, fq, aflo);
        read_a<1>(As1, wm, fr, fq, afhi);
        read_bh<0>(B1h0, wn, fr, fq, bfr);
        BARB();
        mfma_col<0>(acc, aflo, afhi, bfr);
        BARB();
        // ---- P4: tile T1, N-half 1 (stage next-T1 A + B1h0)
        WAITV(8);
        stage_a (Ag, K, kB, As1, 0, wid, lane);
        stage_a (Ag, K, kB, As1, 1, wid, lane);
        stage_bh(Bg, K, kB, B1h0, 0, wid, lane);
        read_bh<1>(B1h1, wn, fr, fq, bfr);
        BARB();
        mfma_col<1>(acc, aflo, afhi, bfr);
        BARB();
    }
    {   // epilogue: tiles NK-2 (buf0), NK-1 (buf1)
        const int kT1 = (NK - 1) * 64;
        // EP1
        WAITV(6);
        stage_bh(Bg, K, kT1, B1h1, 1, wid, lane);
        read_a<0>(As0, wm, fr, fq, aflo);
        read_a<1>(As0, wm, fr, fq, afhi);
        read_bh<0>(B0h0, wn, fr, fq, bfr);
        BARB();
        mfma_col<0>(acc, aflo, afhi, bfr);
        BARB();
        // EP2
        read_bh<1>(B0h1, wn, fr, fq, bfr);
        BARB();
        mfma_col<1>(acc, aflo, afhi, bfr);
        BARB();
        // EP3
        WAITV(2);
        read_a<0>(As1, wm, fr, fq, aflo);
        read_a<1>(As1, wm, fr, fq, afhi);
        read_bh<0>(B1h0, wn, fr, fq, bfr);
        BARB();
        mfma_col<0>(acc, aflo, afhi, bfr);
        BARB();
        // EP4
        WAITV(0);
        read_bh<1>(B1h1, wn, fr, fq, bfr);
        BARB();
        mfma_col<1>(acc, aflo, afhi, bfr);
    }

    // epilogue C write (verified C/D layout: row = fq*4+r, col = fr)
    const int bm = by * 256, bn = bx * 256;
    #pragma unroll
    for (int m = 0; m < 8; ++m) {
        #pragma unroll
        for (int n = 0; n < 4; ++n) {
            #pragma unroll
            for (int r = 0; r < 4; ++r) {
                int row = bm + wm * 128 + m * 16 + fq * 4 + r;
                int col = bn + wn * 64 + n * 16 + fr;
                float v = acc[m][n][r];
                if constexpr (sizeof(OUT_T) == 2)
                    C[(size_t)row * N + col] = (OUT_T)f2bf(v);
                else
                    C[(size_t)row * N + col] = (OUT_T)v;
            }
        }
    }
}

// ---------------- scan helpers ----------------
__device__ inline float phi_f(float z) { return z > 0.f ? z + 1.f : __expf(z); }
__device__ inline float sigmoid_f(float z) { return 1.f / (1.f + __expf(-z)); }

// Pass 1: per-(b,h,chunk) local scan finals (zero init). qkv bf16.
// lane owns dims {2*lane, 2*lane+1} (paired 4B loads).
__global__ void scan_pass1(const unsigned short* __restrict__ qkv,
                           const float* __restrict__ decay_param,
                           float* __restrict__ fkv, float* __restrict__ fk) {
    const int blk = blockIdx.x;
    const int c = blk % NCH;
    const int h = (blk / NCH) % NH;
    const int b = blk / (NCH * NH);
    const int lane = threadIdx.x;
    const float dec = sigmoid_f(decay_param[h]);

    float skv0 = 0.f, skv1 = 0.f, sk0 = 0.f, sk1 = 0.f;
    const unsigned short* base =
        qkv + ((size_t)b * NT + (size_t)c * CHUNK) * QKV_N + h * ND;
    for (int t = 0; t < CHUNK; ++t) {
        const unsigned short* r = base + (size_t)t * QKV_N;
        unsigned kp = *reinterpret_cast<const unsigned*>(r + HID + 2 * lane);
        unsigned vp = *reinterpret_cast<const unsigned*>(r + 2 * HID + 2 * lane);
        float k0 = phi_f(bf2f((unsigned short)(kp & 0xffff)));
        float k1 = phi_f(bf2f((unsigned short)(kp >> 16)));
        float v0 = bf2f((unsigned short)(vp & 0xffff));
        float v1 = bf2f((unsigned short)(vp >> 16));
        skv0 = fmaf(dec, skv0, k0 * v0);
        skv1 = fmaf(dec, skv1, k1 * v1);
        sk0  = fmaf(dec, sk0,  k0);
        sk1  = fmaf(dec, sk1,  k1);
    }
    size_t o = (size_t)blk * ND + 2 * lane;
    *reinterpret_cast<float2*>(&fkv[o]) = make_float2(skv0, skv1);
    *reinterpret_cast<float2*>(&fk[o])  = make_float2(sk0, sk1);
}

// Pass 2: sequential chunk combine; emits carry-ins and final states.
__global__ void scan_pass2(const float* __restrict__ fkv, const float* __restrict__ fk,
                           const float* __restrict__ decay_param,
                           float* __restrict__ ckv, float* __restrict__ ck,
                           float* __restrict__ out_states) {
    const int bh = blockIdx.x;
    const int h = bh % NH;
    const int lane = threadIdx.x;
    const float dec = sigmoid_f(decay_param[h]);
    const float dL = powf(dec, (float)CHUNK);

    float Skv0 = 0.f, Skv1 = 0.f, Sk0 = 0.f, Sk1 = 0.f;
    for (int c = 0; c < NCH; ++c) {
        size_t o = ((size_t)bh * NCH + c) * ND + 2 * lane;
        *reinterpret_cast<float2*>(&ckv[o]) = make_float2(Skv0, Skv1);
        *reinterpret_cast<float2*>(&ck[o])  = make_float2(Sk0, Sk1);
        float2 fv = *reinterpret_cast<const float2*>(&fkv[o]);
        float2 fs = *reinterpret_cast<const float2*>(&fk[o]);
        Skv0 = fmaf(dL, Skv0, fv.x);
        Skv1 = fmaf(dL, Skv1, fv.y);
        Sk0  = fmaf(dL, Sk0,  fs.x);
        Sk1  = fmaf(dL, Sk1,  fs.y);
    }
    size_t so = (size_t)bh * ND + 2 * lane;
    *reinterpret_cast<float2*>(&out_states[so]) = make_float2(Skv0, Skv1);
    *reinterpret_cast<float2*>(&out_states[NB * NH * ND + so]) = make_float2(Sk0, Sk1);
}

// Pass 3: replay with carry-in; writes attn in bf16.
__global__ void scan_pass3(const unsigned short* __restrict__ qkv,
                           const float* __restrict__ decay_param,
                           const float* __restrict__ ckv, const float* __restrict__ ck,
                           unsigned short* __restrict__ attn) {
    const int blk = blockIdx.x;
    const int c = blk % NCH;
    const int h = (blk / NCH) % NH;
    const int b = blk / (NCH * NH);
    const int lane = threadIdx.x;
    const float dec = sigmoid_f(decay_param[h]);

    size_t co = (size_t)blk * ND + 2 * lane;
    float2 cv = *reinterpret_cast<const float2*>(&ckv[co]);
    float2 cs = *reinterpret_cast<const float2*>(&ck[co]);
    float skv0 = cv.x, skv1 = cv.y, sk0 = cs.x, sk1 = cs.y;

    const unsigned short* base =
        qkv + ((size_t)b * NT + (size_t)c * CHUNK) * QKV_N + h * ND;
    unsigned short* abase =
        attn + ((size_t)b * NT + (size_t)c * CHUNK) * HID + h * ND;

    for (int t = 0; t < CHUNK; ++t) {
        const unsigned short* r = base + (size_t)t * QKV_N;
        unsigned qp = *reinterpret_cast<const unsigned*>(r + 2 * lane);
        unsigned kp = *reinterpret_cast<const unsigned*>(r + HID + 2 * lane);
        unsigned vp = *reinterpret_cast<const unsigned*>(r + 2 * HID + 2 * lane);
        float q0 = phi_f(bf2f((unsigned short)(qp & 0xffff)));
        float q1 = phi_f(bf2f((unsigned short)(qp >> 16)));
        float k0 = phi_f(bf2f((unsigned short)(kp & 0xffff)));
        float k1 = phi_f(bf2f((unsigned short)(kp >> 16)));
        float v0 = bf2f((unsigned short)(vp & 0xffff));
        float v1 = bf2f((unsigned short)(vp >> 16));
        skv0 = fmaf(dec, skv0, k0 * v0);
        skv1 = fmaf(dec, skv1, k1 * v1);
        sk0  = fmaf(dec, sk0,  k0);
        sk1  = fmaf(dec, sk1,  k1);
        float den = fmaf(q0, sk0, q1 * sk1);
        #pragma unroll
        for (int m = 1; m < 64; m <<= 1) den += __shfl_xor(den, m, 64);
        den = fmaxf(den, 1e-6f);
        float inv = 1.f / den;
        unsigned o = ((unsigned)f2bf(q1 * skv1 * inv) << 16) |
                     (unsigned)f2bf(q0 * skv0 * inv);
        *reinterpret_cast<unsigned*>(abase + (size_t)t * HID + 2 * lane) = o;
    }
}

// ---------------- launch ----------------
extern "C" void kernel_launch(void* const* d_in, const int* in_sizes, int n_in,
                              void* d_out, int out_size, void* d_ws, size_t ws_size,
                              hipStream_t stream) {
    const float* x      = (const float*)d_in[0];   // [2,4096,2048]
    const float* w_qkv  = (const float*)d_in[1];   // [2048,6144]
    const float* w_out  = (const float*)d_in[2];   // [2048,2048]
    const float* decayp = (const float*)d_in[3];   // [16]
    float* out = (float*)d_out;

    // workspace layout
    char* ws = (char*)d_ws;
    unsigned short* xb     = (unsigned short*)ws;                         // 8192*2048
    unsigned short* wqkvT  = xb    + (size_t)ROWS * HID;                  // 6144*2048
    unsigned short* woutT  = wqkvT + (size_t)QKV_N * HID;                 // 2048*2048
    unsigned short* qkvb   = woutT + (size_t)HID * HID;                   // 8192*6144
    unsigned short* attnb  = qkvb  + (size_t)ROWS * QKV_N;                // 8192*2048
    float* fkv = (float*)(attnb + (size_t)ROWS * HID);
    float* fk  = fkv + (size_t)NB * NH * NCH * ND;
    float* ckv = fk  + (size_t)NB * NH * NCH * ND;
    float* ck  = ckv + (size_t)NB * NH * NCH * ND;

    // casts
    cast_kernel<<<2048, 256, 0, stream>>>(x, xb, (size_t)ROWS * HID / 4);
    dim3 tg1(QKV_N / 32, HID / 32);
    transpose_cast<<<tg1, 256, 0, stream>>>(w_qkv, wqkvT, HID, QKV_N);
    dim3 tg2(HID / 32, HID / 32);
    transpose_cast<<<tg2, 256, 0, stream>>>(w_out, woutT, HID, HID);

    // GEMM1: qkvb = xb @ wqkvT^T   (bf16 out)  grid 32x24=768
    {
        int nbx = QKV_N / 256, nwg = (ROWS / 256) * nbx;
        gemm256<unsigned short><<<nwg, 512, 0, stream>>>(
            xb, wqkvT, qkvb, ROWS, QKV_N, HID, nbx, nwg / 8);
    }

    // chunked decay scans
    scan_pass1<<<NB * NH * NCH, 64, 0, stream>>>(qkvb, decayp, fkv, fk);
    scan_pass2<<<NB * NH, 64, 0, stream>>>(fkv, fk, decayp, ckv, ck,
                                           out + (size_t)ROWS * HID);
    scan_pass3<<<NB * NH * NCH, 64, 0, stream>>>(qkvb, decayp, ckv, ck, attnb);

    // GEMM2: out = attnb @ woutT^T  (f32 out)  grid 32x8=256
    {
        int nbx = HID / 256, nwg = (ROWS / 256) * nbx;
        gemm256<float><<<nwg, 512, 0, stream>>>(
            attnb, woutT, out, ROWS, HID, HID, nbx, nwg / 8);
    }
}

// Round 9
// 365.739 us; speedup vs baseline: 1.1654x; 1.1654x over previous
//
#include <hip/hip_runtime.h>
#include <hip/hip_bf16.h>
#include <stdint.h>

// Problem constants
constexpr int NB = 2;        // batch
constexpr int NT = 4096;     // seq len
constexpr int NH = 16;       // heads
constexpr int ND = 128;      // head dim
constexpr int HID = NH * ND;         // 2048
constexpr int QKV_N = 3 * HID;       // 6144
constexpr int ROWS = NB * NT;        // 8192
constexpr int CHUNK = 64;            // scan chunk length
constexpr int NCH = NT / CHUNK;      // 64 chunks

typedef __bf16 bf16x8 __attribute__((ext_vector_type(8)));
typedef float  f32x4  __attribute__((ext_vector_type(4)));

__device__ inline unsigned short f2bf(float f) {       // RNE fp32->bf16
    unsigned u = __builtin_bit_cast(unsigned, f);
    u += 0x7fffu + ((u >> 16) & 1u);
    return (unsigned short)(u >> 16);
}
__device__ inline float bf2f(unsigned short b) {
    unsigned u = ((unsigned)b) << 16;
    return __builtin_bit_cast(float, u);
}

// ---------------- cast fp32 -> bf16 (flat, float4-vectorized) -------------
__global__ void cast_kernel(const float* __restrict__ in,
                            unsigned short* __restrict__ out, size_t n4) {
    size_t i = blockIdx.x * (size_t)blockDim.x + threadIdx.x;
    size_t stride = (size_t)gridDim.x * blockDim.x;
    for (; i < n4; i += stride) {
        float4 v = reinterpret_cast<const float4*>(in)[i];
        ushort4 o;
        o.x = f2bf(v.x); o.y = f2bf(v.y); o.z = f2bf(v.z); o.w = f2bf(v.w);
        reinterpret_cast<ushort4*>(out)[i] = o;
    }
}

// ------------- transpose + cast: in f32 [R][Cn] -> out bf16 [Cn][R] -------
__global__ __launch_bounds__(256) void transpose_cast(
        const float* __restrict__ in, unsigned short* __restrict__ out,
        int R, int Cn) {
    __shared__ float tile[32][33];
    const int c  = threadIdx.x & 31;
    const int r8 = threadIdx.x >> 5;          // 0..7
    const int r0 = blockIdx.y * 32, c0 = blockIdx.x * 32;
    #pragma unroll
    for (int i = 0; i < 32; i += 8)
        tile[r8 + i][c] = in[(size_t)(r0 + r8 + i) * Cn + c0 + c];
    __syncthreads();
    #pragma unroll
    for (int i = 0; i < 32; i += 8)
        out[(size_t)(c0 + r8 + i) * R + r0 + c] = f2bf(tile[c][r8 + i]);
}

// ============ 128x128 4-wave BK=64 double-buffered GEMM, 2 blocks/CU =======
// Round 9: occupancy pivot. 64 KiB LDS -> TWO independent blocks per CU
// (two barrier domains). When one block's waves sit in the read/stage/
// barrier segment, the other block's waves feed the matrix pipe. Simple
// m97-style prefetch-then-compute loop with __syncthreads (the drain it
// emits is hidden by the co-resident block). setprio around MFMA gets
// genuine cross-block role diversity (T5's regime).

__device__ __forceinline__ void gll(const unsigned short* src, unsigned short* dst) {
    __builtin_amdgcn_global_load_lds(
        (const __attribute__((address_space(1))) void*)src,
        (__attribute__((address_space(3))) void*)dst, 16, 0, 0);
}

// Stage one 128x64 bf16 tile (16 KB): 4 waves x 4 rounds x (64 lanes x 16B).
// Wave covers rows [wid*32, wid*32+32). Linear LDS dest (wave-uniform base +
// lane*16); XOR swizzle realized via inverse-swizzled global source column.
__device__ __forceinline__ void stage_t(const unsigned short* G, int K, int k0,
                                        unsigned short* lds, int wid, int lane) {
    const int rbase = wid * 32;
    const int rl = lane >> 3;                        // 0..7 row within group
    const int ce = ((lane & 7) ^ rl) * 8;            // inverse-swizzled col
    #pragma unroll
    for (int j = 0; j < 4; ++j) {
        gll(G + (size_t)(rbase + j * 8 + rl) * K + k0 + ce,
            lds + (rbase + j * 8) * 64);
    }
}

// swizzled ds_read: row r, k-slot kk*4+fq (8 slots of 8 bf16 across BK=64)
__device__ __forceinline__ bf16x8 ld_frag(const unsigned short* tile,
                                          int r, int kk, int fq) {
    int slot = (kk * 4 + fq) ^ (r & 7);
    return *reinterpret_cast<const bf16x8*>(tile + r * 64 + slot * 8);
}

template <typename OUT_T>
__global__ __launch_bounds__(256, 2) void gemm128(
        const unsigned short* __restrict__ A,   // [M][K] bf16
        const unsigned short* __restrict__ Bt,  // [N][K] bf16
        OUT_T* __restrict__ C,                  // [M][N]
        int M, int N, int K, int nbx, int cpx) {
    __shared__ unsigned short As0[128 * 64];
    __shared__ unsigned short As1[128 * 64];
    __shared__ unsigned short Bs0[128 * 64];
    __shared__ unsigned short Bs1[128 * 64];

    const int bid = blockIdx.x;
    const int wk  = (bid & 7) * cpx + (bid >> 3);   // T1 XCD swizzle (nwg%8==0)
    const int bx  = wk % nbx, by = wk / nbx;
    const int tid = threadIdx.x, wid = tid >> 6, lane = tid & 63;
    const int wm  = wid >> 1, wn = wid & 1;         // 2x2 waves, 64x64 each
    const int fr  = lane & 15, fq = lane >> 4;

    const unsigned short* Ag = A  + (size_t)by * 128 * K;
    const unsigned short* Bg = Bt + (size_t)bx * 128 * K;

    f32x4 acc[4][4] = {};

    stage_t(Ag, K, 0, As0, wid, lane);
    stage_t(Bg, K, 0, Bs0, wid, lane);
    __syncthreads();

    const int NK = K / 64;
    for (int t = 0; t < NK; ++t) {
        const unsigned short* Ac = (t & 1) ? As1 : As0;
        const unsigned short* Bc = (t & 1) ? Bs1 : Bs0;
        if (t + 1 < NK) {   // prefetch next K-tile into the other buffer
            unsigned short* An = (t & 1) ? As0 : As1;
            unsigned short* Bn = (t & 1) ? Bs0 : Bs1;
            stage_t(Ag, K, (t + 1) * 64, An, wid, lane);
            stage_t(Bg, K, (t + 1) * 64, Bn, wid, lane);
        }
        bf16x8 af[4][2], bf[4][2];
        #pragma unroll
        for (int m = 0; m < 4; ++m) {
            int r = wm * 64 + m * 16 + fr;
            af[m][0] = ld_frag(Ac, r, 0, fq);
            af[m][1] = ld_frag(Ac, r, 1, fq);
        }
        #pragma unroll
        for (int n = 0; n < 4; ++n) {
            int r = wn * 64 + n * 16 + fr;
            bf[n][0] = ld_frag(Bc, r, 0, fq);
            bf[n][1] = ld_frag(Bc, r, 1, fq);
        }
        __builtin_amdgcn_s_setprio(1);
        #pragma unroll
        for (int kk = 0; kk < 2; ++kk)
            #pragma unroll
            for (int m = 0; m < 4; ++m)
                #pragma unroll
                for (int n = 0; n < 4; ++n)
                    acc[m][n] = __builtin_amdgcn_mfma_f32_16x16x32_bf16(
                        af[m][kk], bf[n][kk], acc[m][n], 0, 0, 0);
        __builtin_amdgcn_s_setprio(0);
        __syncthreads();
    }

    // C write (verified C/D layout: row = fq*4+r, col = fr)
    const int bm = by * 128, bn = bx * 128;
    #pragma unroll
    for (int m = 0; m < 4; ++m) {
        #pragma unroll
        for (int n = 0; n < 4; ++n) {
            #pragma unroll
            for (int r = 0; r < 4; ++r) {
                int row = bm + wm * 64 + m * 16 + fq * 4 + r;
                int col = bn + wn * 64 + n * 16 + fr;
                float v = acc[m][n][r];
                if constexpr (sizeof(OUT_T) == 2)
                    C[(size_t)row * N + col] = (OUT_T)f2bf(v);
                else
                    C[(size_t)row * N + col] = (OUT_T)v;
            }
        }
    }
}

// ---------------- scan helpers ----------------
__device__ inline float phi_f(float z) { return z > 0.f ? z + 1.f : __expf(z); }
__device__ inline float sigmoid_f(float z) { return 1.f / (1.f + __expf(-z)); }

// Pass 1: per-(b,h,chunk) local scan finals (zero init). qkv bf16.
// lane owns dims {2*lane, 2*lane+1} (paired 4B loads).
__global__ void scan_pass1(const unsigned short* __restrict__ qkv,
                           const float* __restrict__ decay_param,
                           float* __restrict__ fkv, float* __restrict__ fk) {
    const int blk = blockIdx.x;
    const int c = blk % NCH;
    const int h = (blk / NCH) % NH;
    const int b = blk / (NCH * NH);
    const int lane = threadIdx.x;
    const float dec = sigmoid_f(decay_param[h]);

    float skv0 = 0.f, skv1 = 0.f, sk0 = 0.f, sk1 = 0.f;
    const unsigned short* base =
        qkv + ((size_t)b * NT + (size_t)c * CHUNK) * QKV_N + h * ND;
    for (int t = 0; t < CHUNK; ++t) {
        const unsigned short* r = base + (size_t)t * QKV_N;
        unsigned kp = *reinterpret_cast<const unsigned*>(r + HID + 2 * lane);
        unsigned vp = *reinterpret_cast<const unsigned*>(r + 2 * HID + 2 * lane);
        float k0 = phi_f(bf2f((unsigned short)(kp & 0xffff)));
        float k1 = phi_f(bf2f((unsigned short)(kp >> 16)));
        float v0 = bf2f((unsigned short)(vp & 0xffff));
        float v1 = bf2f((unsigned short)(vp >> 16));
        skv0 = fmaf(dec, skv0, k0 * v0);
        skv1 = fmaf(dec, skv1, k1 * v1);
        sk0  = fmaf(dec, sk0,  k0);
        sk1  = fmaf(dec, sk1,  k1);
    }
    size_t o = (size_t)blk * ND + 2 * lane;
    *reinterpret_cast<float2*>(&fkv[o]) = make_float2(skv0, skv1);
    *reinterpret_cast<float2*>(&fk[o])  = make_float2(sk0, sk1);
}

// Pass 2: sequential chunk combine; emits carry-ins and final states.
__global__ void scan_pass2(const float* __restrict__ fkv, const float* __restrict__ fk,
                           const float* __restrict__ decay_param,
                           float* __restrict__ ckv, float* __restrict__ ck,
                           float* __restrict__ out_states) {
    const int bh = blockIdx.x;
    const int h = bh % NH;
    const int lane = threadIdx.x;
    const float dec = sigmoid_f(decay_param[h]);
    const float dL = powf(dec, (float)CHUNK);

    float Skv0 = 0.f, Skv1 = 0.f, Sk0 = 0.f, Sk1 = 0.f;
    for (int c = 0; c < NCH; ++c) {
        size_t o = ((size_t)bh * NCH + c) * ND + 2 * lane;
        *reinterpret_cast<float2*>(&ckv[o]) = make_float2(Skv0, Skv1);
        *reinterpret_cast<float2*>(&ck[o])  = make_float2(Sk0, Sk1);
        float2 fv = *reinterpret_cast<const float2*>(&fkv[o]);
        float2 fs = *reinterpret_cast<const float2*>(&fk[o]);
        Skv0 = fmaf(dL, Skv0, fv.x);
        Skv1 = fmaf(dL, Skv1, fv.y);
        Sk0  = fmaf(dL, Sk0,  fs.x);
        Sk1  = fmaf(dL, Sk1,  fs.y);
    }
    size_t so = (size_t)bh * ND + 2 * lane;
    *reinterpret_cast<float2*>(&out_states[so]) = make_float2(Skv0, Skv1);
    *reinterpret_cast<float2*>(&out_states[NB * NH * ND + so]) = make_float2(Sk0, Sk1);
}

// Pass 3: replay with carry-in; writes attn in bf16.
__global__ void scan_pass3(const unsigned short* __restrict__ qkv,
                           const float* __restrict__ decay_param,
                           const float* __restrict__ ckv, const float* __restrict__ ck,
                           unsigned short* __restrict__ attn) {
    const int blk = blockIdx.x;
    const int c = blk % NCH;
    const int h = (blk / NCH) % NH;
    const int b = blk / (NCH * NH);
    const int lane = threadIdx.x;
    const float dec = sigmoid_f(decay_param[h]);

    size_t co = (size_t)blk * ND + 2 * lane;
    float2 cv = *reinterpret_cast<const float2*>(&ckv[co]);
    float2 cs = *reinterpret_cast<const float2*>(&ck[co]);
    float skv0 = cv.x, skv1 = cv.y, sk0 = cs.x, sk1 = cs.y;

    const unsigned short* base =
        qkv + ((size_t)b * NT + (size_t)c * CHUNK) * QKV_N + h * ND;
    unsigned short* abase =
        attn + ((size_t)b * NT + (size_t)c * CHUNK) * HID + h * ND;

    for (int t = 0; t < CHUNK; ++t) {
        const unsigned short* r = base + (size_t)t * QKV_N;
        unsigned qp = *reinterpret_cast<const unsigned*>(r + 2 * lane);
        unsigned kp = *reinterpret_cast<const unsigned*>(r + HID + 2 * lane);
        unsigned vp = *reinterpret_cast<const unsigned*>(r + 2 * HID + 2 * lane);
        float q0 = phi_f(bf2f((unsigned short)(qp & 0xffff)));
        float q1 = phi_f(bf2f((unsigned short)(qp >> 16)));
        float k0 = phi_f(bf2f((unsigned short)(kp & 0xffff)));
        float k1 = phi_f(bf2f((unsigned short)(kp >> 16)));
        float v0 = bf2f((unsigned short)(vp & 0xffff));
        float v1 = bf2f((unsigned short)(vp >> 16));
        skv0 = fmaf(dec, skv0, k0 * v0);
        skv1 = fmaf(dec, skv1, k1 * v1);
        sk0  = fmaf(dec, sk0,  k0);
        sk1  = fmaf(dec, sk1,  k1);
        float den = fmaf(q0, sk0, q1 * sk1);
        #pragma unroll
        for (int m = 1; m < 64; m <<= 1) den += __shfl_xor(den, m, 64);
        den = fmaxf(den, 1e-6f);
        float inv = 1.f / den;
        unsigned o = ((unsigned)f2bf(q1 * skv1 * inv) << 16) |
                     (unsigned)f2bf(q0 * skv0 * inv);
        *reinterpret_cast<unsigned*>(abase + (size_t)t * HID + 2 * lane) = o;
    }
}

// ---------------- launch ----------------
extern "C" void kernel_launch(void* const* d_in, const int* in_sizes, int n_in,
                              void* d_out, int out_size, void* d_ws, size_t ws_size,
                              hipStream_t stream) {
    const float* x      = (const float*)d_in[0];   // [2,4096,2048]
    const float* w_qkv  = (const float*)d_in[1];   // [2048,6144]
    const float* w_out  = (const float*)d_in[2];   // [2048,2048]
    const float* decayp = (const float*)d_in[3];   // [16]
    float* out = (float*)d_out;

    // workspace layout
    char* ws = (char*)d_ws;
    unsigned short* xb     = (unsigned short*)ws;                         // 8192*2048
    unsigned short* wqkvT  = xb    + (size_t)ROWS * HID;                  // 6144*2048
    unsigned short* woutT  = wqkvT + (size_t)QKV_N * HID;                 // 2048*2048
    unsigned short* qkvb   = woutT + (size_t)HID * HID;                   // 8192*6144
    unsigned short* attnb  = qkvb  + (size_t)ROWS * QKV_N;                // 8192*2048
    float* fkv = (float*)(attnb + (size_t)ROWS * HID);
    float* fk  = fkv + (size_t)NB * NH * NCH * ND;
    float* ckv = fk  + (size_t)NB * NH * NCH * ND;
    float* ck  = ckv + (size_t)NB * NH * NCH * ND;

    // casts
    cast_kernel<<<2048, 256, 0, stream>>>(x, xb, (size_t)ROWS * HID / 4);
    dim3 tg1(QKV_N / 32, HID / 32);
    transpose_cast<<<tg1, 256, 0, stream>>>(w_qkv, wqkvT, HID, QKV_N);
    dim3 tg2(HID / 32, HID / 32);
    transpose_cast<<<tg2, 256, 0, stream>>>(w_out, woutT, HID, HID);

    // GEMM1: qkvb = xb @ wqkvT^T   (bf16 out)  grid 64x48 = 3072 blocks
    {
        int nbx = QKV_N / 128, nwg = (ROWS / 128) * nbx;
        gemm128<unsigned short><<<nwg, 256, 0, stream>>>(
            xb, wqkvT, qkvb, ROWS, QKV_N, HID, nbx, nwg / 8);
    }

    // chunked decay scans
    scan_pass1<<<NB * NH * NCH, 64, 0, stream>>>(qkvb, decayp, fkv, fk);
    scan_pass2<<<NB * NH, 64, 0, stream>>>(fkv, fk, decayp, ckv, ck,
                                           out + (size_t)ROWS * HID);
    scan_pass3<<<NB * NH * NCH, 64, 0, stream>>>(qkvb, decayp, ckv, ck, attnb);

    // GEMM2: out = attnb @ woutT^T  (f32 out)  grid 64x16 = 1024 blocks
    {
        int nbx = HID / 128, nwg = (ROWS / 128) * nbx;
        gemm128<float><<<nwg, 256, 0, stream>>>(
            attnb, woutT, out, ROWS, HID, HID, nbx, nwg / 8);
    }
}

// Round 10
// 354.238 us; speedup vs baseline: 1.2032x; 1.0325x over previous
//
#include <hip/hip_runtime.h>
#include <hip/hip_bf16.h>
#include <stdint.h>

// Problem constants
constexpr int NB = 2;        // batch
constexpr int NT = 4096;     // seq len
constexpr int NH = 16;       // heads
constexpr int ND = 128;      // head dim
constexpr int HID = NH * ND;         // 2048
constexpr int QKV_N = 3 * HID;       // 6144
constexpr int ROWS = NB * NT;        // 8192
constexpr int CHUNK = 64;            // scan chunk length
constexpr int NCH = NT / CHUNK;      // 64 chunks

typedef __bf16 bf16x8 __attribute__((ext_vector_type(8)));
typedef float  f32x4  __attribute__((ext_vector_type(4)));

__device__ inline unsigned short f2bf(float f) {       // RNE fp32->bf16
    unsigned u = __builtin_bit_cast(unsigned, f);
    u += 0x7fffu + ((u >> 16) & 1u);
    return (unsigned short)(u >> 16);
}
__device__ inline float bf2f(unsigned short b) {
    unsigned u = ((unsigned)b) << 16;
    return __builtin_bit_cast(float, u);
}

// ---------------- cast fp32 -> bf16 (flat, float4-vectorized) -------------
__global__ void cast_kernel(const float* __restrict__ in,
                            unsigned short* __restrict__ out, size_t n4) {
    size_t i = blockIdx.x * (size_t)blockDim.x + threadIdx.x;
    size_t stride = (size_t)gridDim.x * blockDim.x;
    for (; i < n4; i += stride) {
        float4 v = reinterpret_cast<const float4*>(in)[i];
        ushort4 o;
        o.x = f2bf(v.x); o.y = f2bf(v.y); o.z = f2bf(v.z); o.w = f2bf(v.w);
        reinterpret_cast<ushort4*>(out)[i] = o;
    }
}

// ------------- transpose + cast: in f32 [R][Cn] -> out bf16 [Cn][R] -------
__global__ __launch_bounds__(256) void transpose_cast(
        const float* __restrict__ in, unsigned short* __restrict__ out,
        int R, int Cn) {
    __shared__ float tile[32][33];
    const int c  = threadIdx.x & 31;
    const int r8 = threadIdx.x >> 5;          // 0..7
    const int r0 = blockIdx.y * 32, c0 = blockIdx.x * 32;
    #pragma unroll
    for (int i = 0; i < 32; i += 8)
        tile[r8 + i][c] = in[(size_t)(r0 + r8 + i) * Cn + c0 + c];
    __syncthreads();
    #pragma unroll
    for (int i = 0; i < 32; i += 8)
        out[(size_t)(c0 + r8 + i) * R + r0 + c] = f2bf(tile[c][r8 + i]);
}

// ============ 128x128 4-wave BK=64 double-buffered GEMM, 2 blocks/CU =======
// Round 10: identical compute/schedule to round 9; ONLY the block->tile
// mapping changes. Each XCD gets a contiguous bid-chunk (bid&7 = XCD) and
// traverses it COLUMN-MAJOR over an 8-wide by-band: by = xcd*8 + c%8,
// bx = c/8. The ~64 co-resident blocks per XCD then cover an 8x8 tile
// window (8 A-panels + 8 B-panels = 8 MB, mostly L2-resident) instead of
// 1-2 A-panels x all B-panels (25 MB). Cuts HBM re-fetch of B.

__device__ __forceinline__ void gll(const unsigned short* src, unsigned short* dst) {
    __builtin_amdgcn_global_load_lds(
        (const __attribute__((address_space(1))) void*)src,
        (__attribute__((address_space(3))) void*)dst, 16, 0, 0);
}

// Stage one 128x64 bf16 tile (16 KB): 4 waves x 4 rounds x (64 lanes x 16B).
__device__ __forceinline__ void stage_t(const unsigned short* G, int K, int k0,
                                        unsigned short* lds, int wid, int lane) {
    const int rbase = wid * 32;
    const int rl = lane >> 3;                        // 0..7 row within group
    const int ce = ((lane & 7) ^ rl) * 8;            // inverse-swizzled col
    #pragma unroll
    for (int j = 0; j < 4; ++j) {
        gll(G + (size_t)(rbase + j * 8 + rl) * K + k0 + ce,
            lds + (rbase + j * 8) * 64);
    }
}

// swizzled ds_read: row r, k-slot kk*4+fq (8 slots of 8 bf16 across BK=64)
__device__ __forceinline__ bf16x8 ld_frag(const unsigned short* tile,
                                          int r, int kk, int fq) {
    int slot = (kk * 4 + fq) ^ (r & 7);
    return *reinterpret_cast<const bf16x8*>(tile + r * 64 + slot * 8);
}

template <typename OUT_T>
__global__ __launch_bounds__(256, 2) void gemm128(
        const unsigned short* __restrict__ A,   // [M][K] bf16
        const unsigned short* __restrict__ Bt,  // [N][K] bf16
        OUT_T* __restrict__ C,                  // [M][N]
        int M, int N, int K, int byc) {
    __shared__ unsigned short As0[128 * 64];
    __shared__ unsigned short As1[128 * 64];
    __shared__ unsigned short Bs0[128 * 64];
    __shared__ unsigned short Bs1[128 * 64];

    const int bid = blockIdx.x;
    const int xcd = bid & 7;
    const int c   = bid >> 3;
    const int by  = xcd * byc + (c % byc);   // 8-wide by-band per XCD
    const int bx  = c / byc;                 // column-major within band
    const int tid = threadIdx.x, wid = tid >> 6, lane = tid & 63;
    const int wm  = wid >> 1, wn = wid & 1;         // 2x2 waves, 64x64 each
    const int fr  = lane & 15, fq = lane >> 4;

    const unsigned short* Ag = A  + (size_t)by * 128 * K;
    const unsigned short* Bg = Bt + (size_t)bx * 128 * K;

    f32x4 acc[4][4] = {};

    stage_t(Ag, K, 0, As0, wid, lane);
    stage_t(Bg, K, 0, Bs0, wid, lane);
    __syncthreads();

    const int NK = K / 64;
    for (int t = 0; t < NK; ++t) {
        const unsigned short* Ac = (t & 1) ? As1 : As0;
        const unsigned short* Bc = (t & 1) ? Bs1 : Bs0;
        if (t + 1 < NK) {   // prefetch next K-tile into the other buffer
            unsigned short* An = (t & 1) ? As0 : As1;
            unsigned short* Bn = (t & 1) ? Bs0 : Bs1;
            stage_t(Ag, K, (t + 1) * 64, An, wid, lane);
            stage_t(Bg, K, (t + 1) * 64, Bn, wid, lane);
        }
        bf16x8 af[4][2], bf[4][2];
        #pragma unroll
        for (int m = 0; m < 4; ++m) {
            int r = wm * 64 + m * 16 + fr;
            af[m][0] = ld_frag(Ac, r, 0, fq);
            af[m][1] = ld_frag(Ac, r, 1, fq);
        }
        #pragma unroll
        for (int n = 0; n < 4; ++n) {
            int r = wn * 64 + n * 16 + fr;
            bf[n][0] = ld_frag(Bc, r, 0, fq);
            bf[n][1] = ld_frag(Bc, r, 1, fq);
        }
        __builtin_amdgcn_s_setprio(1);
        #pragma unroll
        for (int kk = 0; kk < 2; ++kk)
            #pragma unroll
            for (int m = 0; m < 4; ++m)
                #pragma unroll
                for (int n = 0; n < 4; ++n)
                    acc[m][n] = __builtin_amdgcn_mfma_f32_16x16x32_bf16(
                        af[m][kk], bf[n][kk], acc[m][n], 0, 0, 0);
        __builtin_amdgcn_s_setprio(0);
        __syncthreads();
    }

    // C write (verified C/D layout: row = fq*4+r, col = fr)
    const int bm = by * 128, bn = bx * 128;
    #pragma unroll
    for (int m = 0; m < 4; ++m) {
        #pragma unroll
        for (int n = 0; n < 4; ++n) {
            #pragma unroll
            for (int r = 0; r < 4; ++r) {
                int row = bm + wm * 64 + m * 16 + fq * 4 + r;
                int col = bn + wn * 64 + n * 16 + fr;
                float v = acc[m][n][r];
                if constexpr (sizeof(OUT_T) == 2)
                    C[(size_t)row * N + col] = (OUT_T)f2bf(v);
                else
                    C[(size_t)row * N + col] = (OUT_T)v;
            }
        }
    }
}

// ---------------- scan helpers ----------------
__device__ inline float phi_f(float z) { return z > 0.f ? z + 1.f : __expf(z); }
__device__ inline float sigmoid_f(float z) { return 1.f / (1.f + __expf(-z)); }

// Pass 1: per-(b,h,chunk) local scan finals (zero init). qkv bf16.
// lane owns dims {2*lane, 2*lane+1} (paired 4B loads).
__global__ void scan_pass1(const unsigned short* __restrict__ qkv,
                           const float* __restrict__ decay_param,
                           float* __restrict__ fkv, float* __restrict__ fk) {
    const int blk = blockIdx.x;
    const int c = blk % NCH;
    const int h = (blk / NCH) % NH;
    const int b = blk / (NCH * NH);
    const int lane = threadIdx.x;
    const float dec = sigmoid_f(decay_param[h]);

    float skv0 = 0.f, skv1 = 0.f, sk0 = 0.f, sk1 = 0.f;
    const unsigned short* base =
        qkv + ((size_t)b * NT + (size_t)c * CHUNK) * QKV_N + h * ND;
    for (int t = 0; t < CHUNK; ++t) {
        const unsigned short* r = base + (size_t)t * QKV_N;
        unsigned kp = *reinterpret_cast<const unsigned*>(r + HID + 2 * lane);
        unsigned vp = *reinterpret_cast<const unsigned*>(r + 2 * HID + 2 * lane);
        float k0 = phi_f(bf2f((unsigned short)(kp & 0xffff)));
        float k1 = phi_f(bf2f((unsigned short)(kp >> 16)));
        float v0 = bf2f((unsigned short)(vp & 0xffff));
        float v1 = bf2f((unsigned short)(vp >> 16));
        skv0 = fmaf(dec, skv0, k0 * v0);
        skv1 = fmaf(dec, skv1, k1 * v1);
        sk0  = fmaf(dec, sk0,  k0);
        sk1  = fmaf(dec, sk1,  k1);
    }
    size_t o = (size_t)blk * ND + 2 * lane;
    *reinterpret_cast<float2*>(&fkv[o]) = make_float2(skv0, skv1);
    *reinterpret_cast<float2*>(&fk[o])  = make_float2(sk0, sk1);
}

// Pass 2: sequential chunk combine; emits carry-ins and final states.
__global__ void scan_pass2(const float* __restrict__ fkv, const float* __restrict__ fk,
                           const float* __restrict__ decay_param,
                           float* __restrict__ ckv, float* __restrict__ ck,
                           float* __restrict__ out_states) {
    const int bh = blockIdx.x;
    const int h = bh % NH;
    const int lane = threadIdx.x;
    const float dec = sigmoid_f(decay_param[h]);
    const float dL = powf(dec, (float)CHUNK);

    float Skv0 = 0.f, Skv1 = 0.f, Sk0 = 0.f, Sk1 = 0.f;
    for (int c = 0; c < NCH; ++c) {
        size_t o = ((size_t)bh * NCH + c) * ND + 2 * lane;
        *reinterpret_cast<float2*>(&ckv[o]) = make_float2(Skv0, Skv1);
        *reinterpret_cast<float2*>(&ck[o])  = make_float2(Sk0, Sk1);
        float2 fv = *reinterpret_cast<const float2*>(&fkv[o]);
        float2 fs = *reinterpret_cast<const float2*>(&fk[o]);
        Skv0 = fmaf(dL, Skv0, fv.x);
        Skv1 = fmaf(dL, Skv1, fv.y);
        Sk0  = fmaf(dL, Sk0,  fs.x);
        Sk1  = fmaf(dL, Sk1,  fs.y);
    }
    size_t so = (size_t)bh * ND + 2 * lane;
    *reinterpret_cast<float2*>(&out_states[so]) = make_float2(Skv0, Skv1);
    *reinterpret_cast<float2*>(&out_states[NB * NH * ND + so]) = make_float2(Sk0, Sk1);
}

// Pass 3: replay with carry-in; writes attn in bf16.
__global__ void scan_pass3(const unsigned short* __restrict__ qkv,
                           const float* __restrict__ decay_param,
                           const float* __restrict__ ckv, const float* __restrict__ ck,
                           unsigned short* __restrict__ attn) {
    const int blk = blockIdx.x;
    const int c = blk % NCH;
    const int h = (blk / NCH) % NH;
    const int b = blk / (NCH * NH);
    const int lane = threadIdx.x;
    const float dec = sigmoid_f(decay_param[h]);

    size_t co = (size_t)blk * ND + 2 * lane;
    float2 cv = *reinterpret_cast<const float2*>(&ckv[co]);
    float2 cs = *reinterpret_cast<const float2*>(&ck[co]);
    float skv0 = cv.x, skv1 = cv.y, sk0 = cs.x, sk1 = cs.y;

    const unsigned short* base =
        qkv + ((size_t)b * NT + (size_t)c * CHUNK) * QKV_N + h * ND;
    unsigned short* abase =
        attn + ((size_t)b * NT + (size_t)c * CHUNK) * HID + h * ND;

    for (int t = 0; t < CHUNK; ++t) {
        const unsigned short* r = base + (size_t)t * QKV_N;
        unsigned qp = *reinterpret_cast<const unsigned*>(r + 2 * lane);
        unsigned kp = *reinterpret_cast<const unsigned*>(r + HID + 2 * lane);
        unsigned vp = *reinterpret_cast<const unsigned*>(r + 2 * HID + 2 * lane);
        float q0 = phi_f(bf2f((unsigned short)(qp & 0xffff)));
        float q1 = phi_f(bf2f((unsigned short)(qp >> 16)));
        float k0 = phi_f(bf2f((unsigned short)(kp & 0xffff)));
        float k1 = phi_f(bf2f((unsigned short)(kp >> 16)));
        float v0 = bf2f((unsigned short)(vp & 0xffff));
        float v1 = bf2f((unsigned short)(vp >> 16));
        skv0 = fmaf(dec, skv0, k0 * v0);
        skv1 = fmaf(dec, skv1, k1 * v1);
        sk0  = fmaf(dec, sk0,  k0);
        sk1  = fmaf(dec, sk1,  k1);
        float den = fmaf(q0, sk0, q1 * sk1);
        #pragma unroll
        for (int m = 1; m < 64; m <<= 1) den += __shfl_xor(den, m, 64);
        den = fmaxf(den, 1e-6f);
        float inv = 1.f / den;
        unsigned o = ((unsigned)f2bf(q1 * skv1 * inv) << 16) |
                     (unsigned)f2bf(q0 * skv0 * inv);
        *reinterpret_cast<unsigned*>(abase + (size_t)t * HID + 2 * lane) = o;
    }
}

// ---------------- launch ----------------
extern "C" void kernel_launch(void* const* d_in, const int* in_sizes, int n_in,
                              void* d_out, int out_size, void* d_ws, size_t ws_size,
                              hipStream_t stream) {
    const float* x      = (const float*)d_in[0];   // [2,4096,2048]
    const float* w_qkv  = (const float*)d_in[1];   // [2048,6144]
    const float* w_out  = (const float*)d_in[2];   // [2048,2048]
    const float* decayp = (const float*)d_in[3];   // [16]
    float* out = (float*)d_out;

    // workspace layout
    char* ws = (char*)d_ws;
    unsigned short* xb     = (unsigned short*)ws;                         // 8192*2048
    unsigned short* wqkvT  = xb    + (size_t)ROWS * HID;                  // 6144*2048
    unsigned short* woutT  = wqkvT + (size_t)QKV_N * HID;                 // 2048*2048
    unsigned short* qkvb   = woutT + (size_t)HID * HID;                   // 8192*6144
    unsigned short* attnb  = qkvb  + (size_t)ROWS * QKV_N;                // 8192*2048
    float* fkv = (float*)(attnb + (size_t)ROWS * HID);
    float* fk  = fkv + (size_t)NB * NH * NCH * ND;
    float* ckv = fk  + (size_t)NB * NH * NCH * ND;
    float* ck  = ckv + (size_t)NB * NH * NCH * ND;

    // casts
    cast_kernel<<<2048, 256, 0, stream>>>(x, xb, (size_t)ROWS * HID / 4);
    dim3 tg1(QKV_N / 32, HID / 32);
    transpose_cast<<<tg1, 256, 0, stream>>>(w_qkv, wqkvT, HID, QKV_N);
    dim3 tg2(HID / 32, HID / 32);
    transpose_cast<<<tg2, 256, 0, stream>>>(w_out, woutT, HID, HID);

    // GEMM1: qkvb = xb @ wqkvT^T   (bf16 out)  grid 64x48 = 3072 blocks
    {
        int nby = ROWS / 128, nbx = QKV_N / 128;
        gemm128<unsigned short><<<nby * nbx, 256, 0, stream>>>(
            xb, wqkvT, qkvb, ROWS, QKV_N, HID, nby / 8);
    }

    // chunked decay scans
    scan_pass1<<<NB * NH * NCH, 64, 0, stream>>>(qkvb, decayp, fkv, fk);
    scan_pass2<<<NB * NH, 64, 0, stream>>>(fkv, fk, decayp, ckv, ck,
                                           out + (size_t)ROWS * HID);
    scan_pass3<<<NB * NH * NCH, 64, 0, stream>>>(qkvb, decayp, ckv, ck, attnb);

    // GEMM2: out = attnb @ woutT^T  (f32 out)  grid 64x16 = 1024 blocks
    {
        int nby = ROWS / 128, nbx = HID / 128;
        gemm128<float><<<nby * nbx, 256, 0, stream>>>(
            attnb, woutT, out, ROWS, HID, HID, nby / 8);
    }
}